// Round 3
// baseline (8180.843 us; speedup 1.0000x reference)
//
#include <hip/hip_runtime.h>

// TrajectoryDecoder: 2-layer LSTM (H=256), 45 steps, B=4096.
// MFMA bf16 version: 256 WGs x 16 batches, 4 waves, persistent rollout.
// Weights pre-converted to bf16 in d_ws; h-state bf16 in XOR-swizzled LDS;
// c-state + gctx + pos fp32. mfma_f32_16x16x32_bf16, m97-verified layout:
//   A(first op): row=lane&15 (batch), k=(lane>>4)*8+j   (8 contiguous bf16)
//   B(second op, "B^T"): col=lane&15 (gate row of W), k contiguous
//   C/D: row=(lane>>4)*4+q (batch), col=lane&15 (gate)

#define BB    16
#define TPB   256
#define HN    256
#define DM    128
#define NSTEP 45

typedef __attribute__((ext_vector_type(8))) short s8v;
typedef __attribute__((ext_vector_type(4))) float f32x4;

#define MFMA16(a,b,c) __builtin_amdgcn_mfma_f32_16x16x32_bf16((a),(b),(c),0,0,0)

__device__ __forceinline__ unsigned short f2bf(float f){
  union { float f; unsigned u; } x; x.f = f;
  unsigned r = x.u + 0x7fffu + ((x.u >> 16) & 1u);
  return (unsigned short)(r >> 16);
}
__device__ __forceinline__ float sigm(float x){
  x = fminf(40.f, fmaxf(-40.f, x));
  return 1.f/(1.f + __expf(-x));
}
__device__ __forceinline__ float tanhx(float x){
  float xx = fminf(15.f, fmaxf(-15.f, x));
  float e = __expf(2.f*xx);
  return (e-1.f)/(e+1.f);
}

// h LDS: bf16 [16 rows][256], row b element u stored at u ^ ((b&7)<<3)
__device__ __forceinline__ void write_h(unsigned short* lds, int b, int u, float v){
  lds[b*HN + (u ^ ((b&7)<<3))] = f2bf(v);
}
__device__ __forceinline__ s8v read_afrag(const unsigned short* lds, int b, int hi, int kt){
  int blk = (kt*4 + hi) ^ (b & 7);
  return *(const s8v*)(lds + b*HN + blk*8);
}

// ---- weight fp32 -> bf16 pre-pass into d_ws ----
// layout (ushort elems): Whh0[262144] | Wih1[262144] | Whh1[262144] | Wp1[16384]
__global__ void conv_bf16(const float* __restrict__ w0, const float* __restrict__ w1,
                          const float* __restrict__ w2, const float* __restrict__ wp,
                          unsigned short* __restrict__ dst){
  int i = blockIdx.x*256 + threadIdx.x;
  float v;
  if      (i < 262144) v = w0[i];
  else if (i < 524288) v = w1[i-262144];
  else if (i < 786432) v = w2[i-524288];
  else if (i < 802816) v = wp[i-786432];
  else return;
  dst[i] = f2bf(v);
}

__global__ __launch_bounds__(TPB, 1)
void traj_mfma(const float* __restrict__ enc,   // B x 128
               const float* __restrict__ pos0,  // B x 2
               const float* __restrict__ ctx,   // B x 128
               const float* __restrict__ Wh,    // 512 x 128
               const float* __restrict__ bh,
               const float* __restrict__ Wc,
               const float* __restrict__ bc,
               const float* __restrict__ Wih0,  // 1024 x 130
               const float* __restrict__ bih0,
               const float* __restrict__ bhh0,
               const float* __restrict__ bih1,
               const float* __restrict__ bhh1,
               const float* __restrict__ Wp2,   // 2 x 64
               const float* __restrict__ bp1,   // 64
               const float* __restrict__ bp2,   // 2
               const unsigned short* __restrict__ wsW,
               float* __restrict__ out)         // B x 45 x 2
{
  __shared__ float sh_gctx[BB][4*HN];          // 64KB fp32 gates_ctx (incl bias0)
  __shared__ unsigned short sh_h0u[BB*HN];     // 8KB bf16 swizzled
  __shared__ unsigned short sh_h1u[BB*HN];     // 8KB
  __shared__ float sh_ct0[BB][HN];             // 16KB (init handoff only)
  __shared__ float sh_ct1[BB][HN];             // 16KB
  __shared__ float sh_x[BB][DM];               // 8KB staging
  __shared__ float sh_pos[BB][2];
  __shared__ float sh_red[4][BB][2];

  const int tid  = threadIdx.x;
  const int u    = tid;
  const int gb0  = blockIdx.x * BB;
  const int lane = tid & 63;
  const int w    = tid >> 6;
  const int col  = lane & 15;
  const int hi   = lane >> 4;

  // ---- stage encoder_feat + pos ----
  {
    const float4* src = (const float4*)(enc + (size_t)gb0*DM);
    float4* dst = (float4*)&sh_x[0][0];
    #pragma unroll
    for (int i=0;i<(BB*DM/4)/TPB;i++) dst[tid + i*TPB] = src[tid + i*TPB];
  }
  if (tid < BB*2) ((float*)sh_pos)[tid] = pos0[(size_t)gb0*2 + tid];
  __syncthreads();

  // ---- h/c init (fp32 VALU, one-time) ----
  {
    float a0[BB], a1[BB], a2[BB], a3[BB];
    #pragma unroll
    for (int b=0;b<BB;b++){ a0[b]=0.f;a1[b]=0.f;a2[b]=0.f;a3[b]=0.f; }
    const float4* wh0 = (const float4*)(Wh + (size_t)u*DM);
    const float4* wh1 = (const float4*)(Wh + (size_t)(u+HN)*DM);
    const float4* wc0 = (const float4*)(Wc + (size_t)u*DM);
    const float4* wc1 = (const float4*)(Wc + (size_t)(u+HN)*DM);
    #pragma nounroll
    for (int kk=0; kk<DM/4; kk++){
      float4 w0=wh0[kk], w1=wh1[kk], w2=wc0[kk], w3=wc1[kk];
      #pragma unroll
      for (int b=0;b<BB;b++){
        float4 x = *(const float4*)&sh_x[b][kk*4];
        a0[b] += w0.x*x.x + w0.y*x.y + w0.z*x.z + w0.w*x.w;
        a1[b] += w1.x*x.x + w1.y*x.y + w1.z*x.z + w1.w*x.w;
        a2[b] += w2.x*x.x + w2.y*x.y + w2.z*x.z + w2.w*x.w;
        a3[b] += w3.x*x.x + w3.y*x.y + w3.z*x.z + w3.w*x.w;
      }
    }
    float bh0v = bh[u], bh1v = bh[u+HN], bc0v = bc[u], bc1v = bc[u+HN];
    #pragma unroll
    for (int b=0;b<BB;b++){
      write_h(sh_h0u, b, u, a0[b] + bh0v);
      write_h(sh_h1u, b, u, a1[b] + bh1v);
      sh_ct0[b][u] = a2[b] + bc0v;
      sh_ct1[b][u] = a3[b] + bc1v;
    }
  }
  __syncthreads();

  // ---- stage context ----
  {
    const float4* src = (const float4*)(ctx + (size_t)gb0*DM);
    float4* dst = (float4*)&sh_x[0][0];
    #pragma unroll
    for (int i=0;i<(BB*DM/4)/TPB;i++) dst[tid + i*TPB] = src[tid + i*TPB];
  }
  __syncthreads();

  // ---- gates_ctx = ctx @ Wih0[:,2:]^T + (b_ih0+b_hh0), fp32 ----
  {
    float a[4][BB];
    #pragma unroll
    for (int g=0;g<4;g++){
      #pragma unroll
      for (int b=0;b<BB;b++) a[g][b]=0.f;
    }
    const float2* wr[4];
    #pragma unroll
    for (int g=0;g<4;g++) wr[g] = (const float2*)(Wih0 + (size_t)(u + (g<<8))*130 + 2);
    #pragma nounroll
    for (int kk=0; kk<DM/2; kk++){
      float2 w0=wr[0][kk], w1=wr[1][kk], w2=wr[2][kk], w3=wr[3][kk];
      #pragma unroll
      for (int b=0;b<BB;b++){
        float2 x = *(const float2*)&sh_x[b][kk*2];
        a[0][b] += w0.x*x.x + w0.y*x.y;
        a[1][b] += w1.x*x.x + w1.y*x.y;
        a[2][b] += w2.x*x.x + w2.y*x.y;
        a[3][b] += w3.x*x.x + w3.y*x.y;
      }
    }
    #pragma unroll
    for (int g=0;g<4;g++){
      int j = u + (g<<8);
      float b0 = bih0[j] + bhh0[j];
      #pragma unroll
      for (int b=0;b<BB;b++) sh_gctx[b][j] = a[g][b] + b0;
    }
  }

  // ---- per-lane constants (MFMA-layout ownership) ----
  float wpr[4][4][2]; float b1r[4][4];
  #pragma unroll
  for (int m=0;m<4;m++){
    int uu = (w*4+m)*16 + col;
    #pragma unroll
    for (int g=0;g<4;g++){
      int j = (g<<8) + uu;
      wpr[m][g][0] = Wih0[(size_t)j*130 + 0];
      wpr[m][g][1] = Wih0[(size_t)j*130 + 1];
      b1r[m][g]    = bih1[j] + bhh1[j];
    }
  }
  const int   p    = w*16 + col;
  const float bp1p = bp1[p], w20 = Wp2[p], w21 = Wp2[64+p];
  const float bp20 = bp2[0], bp21 = bp2[1];
  __syncthreads();   // gctx + sh_ct complete

  // ---- c-state into MFMA-layout registers ----
  float c0r[4][4], c1r[4][4];   // [m][q]
  #pragma unroll
  for (int m=0;m<4;m++){
    int uu = (w*4+m)*16 + col;
    #pragma unroll
    for (int q=0;q<4;q++){
      c0r[m][q] = sh_ct0[hi*4+q][uu];
      c1r[m][q] = sh_ct1[hi*4+q][uu];
    }
  }

  const unsigned short* wsWhh0 = wsW;
  const unsigned short* wsWih1 = wsW + 262144;
  const unsigned short* wsWhh1 = wsW + 524288;
  const unsigned short* wsWp1  = wsW + 786432;

  // ================= 45-step rollout =================
  #pragma nounroll
  for (int t=0; t<NSTEP; t++){
    // ---- P1: load A-frags of h0,h1 + pos ----
    s8v a0[8], a1[8];
    #pragma unroll
    for (int kt=0;kt<8;kt++){
      a0[kt] = read_afrag(sh_h0u, col, hi, kt);
      a1[kt] = read_afrag(sh_h1u, col, hi, kt);
    }
    float p0q[4], p1q[4];
    #pragma unroll
    for (int q=0;q<4;q++){
      float2 pp = *(const float2*)&sh_pos[hi*4+q][0];
      p0q[q]=pp.x; p1q[q]=pp.y;
    }
    __syncthreads();

    // ---- P2: layer0 gates + cell ----
    #pragma unroll
    for (int m=0;m<4;m++){
      const int uu = (w*4+m)*16 + col;
      f32x4 ac0, ac1, ac2, ac3;
      #pragma unroll
      for (int q=0;q<4;q++){
        const int b = hi*4+q;
        ac0[q] = sh_gctx[b][uu]     + p0q[q]*wpr[m][0][0] + p1q[q]*wpr[m][0][1];
        ac1[q] = sh_gctx[b][256+uu] + p0q[q]*wpr[m][1][0] + p1q[q]*wpr[m][1][1];
        ac2[q] = sh_gctx[b][512+uu] + p0q[q]*wpr[m][2][0] + p1q[q]*wpr[m][2][1];
        ac3[q] = sh_gctx[b][768+uu] + p0q[q]*wpr[m][3][0] + p1q[q]*wpr[m][3][1];
      }
      const unsigned short* wb = wsWhh0 + (size_t)uu*HN;
      #pragma unroll
      for (int kt=0;kt<8;kt++){
        const int ke = kt*32 + hi*8;
        ac0 = MFMA16(a0[kt], *(const s8v*)(wb + ke),          ac0);
        ac1 = MFMA16(a0[kt], *(const s8v*)(wb + 65536 + ke),  ac1);
        ac2 = MFMA16(a0[kt], *(const s8v*)(wb + 131072 + ke), ac2);
        ac3 = MFMA16(a0[kt], *(const s8v*)(wb + 196608 + ke), ac3);
      }
      #pragma unroll
      for (int q=0;q<4;q++){
        float iv = sigm(ac0[q]), fv = sigm(ac1[q]);
        float gv = tanhx(ac2[q]), ov = sigm(ac3[q]);
        float cv = fv*c0r[m][q] + iv*gv;
        c0r[m][q] = cv;
        write_h(sh_h0u, hi*4+q, uu, ov*tanhx(cv));
      }
    }
    __syncthreads();

    // ---- P3: layer1 gates + cell ----
    s8v a0n[8];
    #pragma unroll
    for (int kt=0;kt<8;kt++) a0n[kt] = read_afrag(sh_h0u, col, hi, kt);
    #pragma unroll
    for (int m=0;m<4;m++){
      const int uu = (w*4+m)*16 + col;
      f32x4 ac0 = {b1r[m][0],b1r[m][0],b1r[m][0],b1r[m][0]};
      f32x4 ac1 = {b1r[m][1],b1r[m][1],b1r[m][1],b1r[m][1]};
      f32x4 ac2 = {b1r[m][2],b1r[m][2],b1r[m][2],b1r[m][2]};
      f32x4 ac3 = {b1r[m][3],b1r[m][3],b1r[m][3],b1r[m][3]};
      const unsigned short* wb1 = wsWih1 + (size_t)uu*HN;
      const unsigned short* wb2 = wsWhh1 + (size_t)uu*HN;
      #pragma unroll
      for (int kt=0;kt<8;kt++){
        const int ke = kt*32 + hi*8;
        ac0 = MFMA16(a0n[kt], *(const s8v*)(wb1 + ke),          ac0);
        ac1 = MFMA16(a0n[kt], *(const s8v*)(wb1 + 65536 + ke),  ac1);
        ac2 = MFMA16(a0n[kt], *(const s8v*)(wb1 + 131072 + ke), ac2);
        ac3 = MFMA16(a0n[kt], *(const s8v*)(wb1 + 196608 + ke), ac3);
      }
      #pragma unroll
      for (int kt=0;kt<8;kt++){
        const int ke = kt*32 + hi*8;
        ac0 = MFMA16(a1[kt], *(const s8v*)(wb2 + ke),          ac0);
        ac1 = MFMA16(a1[kt], *(const s8v*)(wb2 + 65536 + ke),  ac1);
        ac2 = MFMA16(a1[kt], *(const s8v*)(wb2 + 131072 + ke), ac2);
        ac3 = MFMA16(a1[kt], *(const s8v*)(wb2 + 196608 + ke), ac3);
      }
      #pragma unroll
      for (int q=0;q<4;q++){
        float iv = sigm(ac0[q]), fv = sigm(ac1[q]);
        float gv = tanhx(ac2[q]), ov = sigm(ac3[q]);
        float cv = fv*c1r[m][q] + iv*gv;
        c1r[m][q] = cv;
        write_h(sh_h1u, hi*4+q, uu, ov*tanhx(cv));
      }
    }
    __syncthreads();

    // ---- P4: head (hp = relu(h1 @ Wp1^T + bp1)), per-wave p-tile ----
    s8v a1n[8];
    #pragma unroll
    for (int kt=0;kt<8;kt++) a1n[kt] = read_afrag(sh_h1u, col, hi, kt);
    f32x4 hp = {bp1p, bp1p, bp1p, bp1p};
    const unsigned short* wbp = wsWp1 + (size_t)p*HN;
    #pragma unroll
    for (int kt=0;kt<8;kt++){
      hp = MFMA16(a1n[kt], *(const s8v*)(wbp + kt*32 + hi*8), hp);
    }
    #pragma unroll
    for (int q=0;q<4;q++){
      float r  = fmaxf(hp[q], 0.f);
      float s0 = r*w20, s1 = r*w21;
      #pragma unroll
      for (int off=1; off<16; off<<=1){
        s0 += __shfl_xor(s0, off, 64);
        s1 += __shfl_xor(s1, off, 64);
      }
      if (col == 0){ sh_red[w][hi*4+q][0] = s0; sh_red[w][hi*4+q][1] = s1; }
    }
    __syncthreads();

    // ---- P5: combine wave partials, update pos, write out ----
    if (tid < 32){
      int b = tid >> 1, d = tid & 1;
      float s = sh_red[0][b][d] + sh_red[1][b][d] + sh_red[2][b][d] + sh_red[3][b][d]
              + (d ? bp21 : bp20);
      float np = sh_pos[b][d] + s;
      sh_pos[b][d] = np;
      out[((size_t)(gb0+b)*NSTEP + t)*2 + d] = np;
    }
    __syncthreads();
  }
}

extern "C" void kernel_launch(void* const* d_in, const int* in_sizes, int n_in,
                              void* d_out, int out_size, void* d_ws, size_t ws_size,
                              hipStream_t stream) {
  const float* enc  = (const float*)d_in[0];
  const float* pos0 = (const float*)d_in[1];
  const float* ctx  = (const float*)d_in[2];
  const float* Wh   = (const float*)d_in[3];
  const float* bh   = (const float*)d_in[4];
  const float* Wc   = (const float*)d_in[5];
  const float* bc   = (const float*)d_in[6];
  const float* Wih0 = (const float*)d_in[7];
  const float* Whh0 = (const float*)d_in[8];
  const float* bih0 = (const float*)d_in[9];
  const float* bhh0 = (const float*)d_in[10];
  const float* Wih1 = (const float*)d_in[11];
  const float* Whh1 = (const float*)d_in[12];
  const float* bih1 = (const float*)d_in[13];
  const float* bhh1 = (const float*)d_in[14];
  const float* Wp1  = (const float*)d_in[15];
  const float* bp1  = (const float*)d_in[16];
  const float* Wp2  = (const float*)d_in[17];
  const float* bp2  = (const float*)d_in[18];
  float* out = (float*)d_out;
  unsigned short* wsW = (unsigned short*)d_ws;

  // pre-pass: fp32 -> bf16 weight conversion (802816 elems, 1.57 MB in d_ws)
  hipLaunchKernelGGL(conv_bf16, dim3(3136), dim3(256), 0, stream,
                     Whh0, Wih1, Whh1, Wp1, wsW);

  const int B = 4096;
  hipLaunchKernelGGL(traj_mfma, dim3(B / BB), dim3(TPB), 0, stream,
                     enc, pos0, ctx, Wh, bh, Wc, bc, Wih0, bih0, bhh0,
                     bih1, bhh1, Wp2, bp1, bp2, wsW, out);
}

// Round 4
// 5340.855 us; speedup vs baseline: 1.5317x; 1.5317x over previous
//
#include <hip/hip_runtime.h>
#include <hip/hip_bf16.h>

// TrajectoryDecoder: 2-layer LSTM (H=256), 45 steps, B=4096.
// MFMA bf16, weights read fp32 from d_in (L2-resident) + inline cvt to bf16.
// 256 WGs x BB=16 batches, 512 threads (8 waves, 2 waves/SIMD), persistent.
// mfma_f32_16x16x32_bf16 layout (m97-verified):
//   A: row=lane&15 (batch), k=(lane>>4)*8+j ; B("B^T"): col=lane&15 (gate row)
//   C/D: row=(lane>>4)*4+q (batch), col=lane&15 (gate unit)

#define BB    16
#define TPB   512
#define HN    256
#define DM    128
#define NSTEP 45

typedef __attribute__((ext_vector_type(8))) short s8v;
typedef __attribute__((ext_vector_type(4))) float f32x4;

#define MFMA16(a,b,c) __builtin_amdgcn_mfma_f32_16x16x32_bf16((a),(b),(c),0,0,0)

__device__ __forceinline__ unsigned short f2bf(float f){
  union { float f; unsigned u; } x; x.f = f;
  unsigned r = x.u + 0x7fffu + ((x.u >> 16) & 1u);
  return (unsigned short)(r >> 16);
}
__device__ __forceinline__ float sigm(float x){
  x = fminf(40.f, fmaxf(-40.f, x));
  return 1.f/(1.f + __expf(-x));
}
__device__ __forceinline__ float tanhx(float x){
  float xx = fminf(15.f, fmaxf(-15.f, x));
  float e = __expf(2.f*xx);
  return (e-1.f)/(e+1.f);
}
// fp32 x8 -> bf16 x8 (compiler emits v_cvt_pk_bf16_f32)
__device__ __forceinline__ s8v pack8(float4 a, float4 b){
  union { s8v v; __hip_bfloat162 h[4]; } u;
  u.h[0] = __float22bfloat162_rn({a.x, a.y});
  u.h[1] = __float22bfloat162_rn({a.z, a.w});
  u.h[2] = __float22bfloat162_rn({b.x, b.y});
  u.h[3] = __float22bfloat162_rn({b.z, b.w});
  return u.v;
}

// h LDS: bf16 [16 rows][256], row b element u stored at u ^ ((b&7)<<3)
__device__ __forceinline__ void write_h(unsigned short* lds, int b, int u, float v){
  lds[b*HN + (u ^ ((b&7)<<3))] = f2bf(v);
}
__device__ __forceinline__ s8v read_afrag(const unsigned short* lds, int b, int hi, int kt){
  int blk = (kt*4 + hi) ^ (b & 7);
  return *(const s8v*)(lds + b*HN + blk*8);
}

__global__ __launch_bounds__(TPB, 1)
void traj_mfma(const float* __restrict__ enc,   // B x 128
               const float* __restrict__ pos0,  // B x 2
               const float* __restrict__ ctx,   // B x 128
               const float* __restrict__ Wh,    // 512 x 128
               const float* __restrict__ bh,
               const float* __restrict__ Wc,
               const float* __restrict__ bc,
               const float* __restrict__ Wih0,  // 1024 x 130
               const float* __restrict__ Whh0,  // 1024 x 256
               const float* __restrict__ bih0,
               const float* __restrict__ bhh0,
               const float* __restrict__ Wih1,  // 1024 x 256
               const float* __restrict__ Whh1,  // 1024 x 256
               const float* __restrict__ bih1,
               const float* __restrict__ bhh1,
               const float* __restrict__ Wp1,   // 64 x 256
               const float* __restrict__ Wp2,   // 2 x 64
               const float* __restrict__ bp1,
               const float* __restrict__ bp2,
               float* __restrict__ out)         // B x 45 x 2
{
  __shared__ float sh_gctx[BB][4*HN];          // 64KB fp32 gates_ctx (incl bias0)
  __shared__ unsigned short sh_h0u[BB*HN];     // 8KB bf16 swizzled
  __shared__ unsigned short sh_h1u[BB*HN];     // 8KB
  __shared__ float sh_ct0[BB][HN];             // 16KB (init handoff only)
  __shared__ float sh_ct1[BB][HN];             // 16KB
  __shared__ float sh_x[BB][DM];               // 8KB staging
  __shared__ float sh_pos[BB][2];
  __shared__ float sh_red[4][BB][2];

  const int tid  = threadIdx.x;
  const int gb0  = blockIdx.x * BB;
  const int lane = tid & 63;
  const int w    = tid >> 6;        // 8 waves
  const int col  = lane & 15;
  const int hi   = lane >> 4;

  // ---- stage encoder_feat + pos ----
  {
    const float4* src = (const float4*)(enc + (size_t)gb0*DM);
    ((float4*)&sh_x[0][0])[tid] = src[tid];   // 512 float4 = whole tile
  }
  if (tid < BB*2) ((float*)sh_pos)[tid] = pos0[(size_t)gb0*2 + tid];
  __syncthreads();

  // ---- h/c init: thread r computes h_all row r and c_all row r ----
  {
    const int r = tid;   // 0..511
    float ah[BB], ac[BB];
    #pragma unroll
    for (int b=0;b<BB;b++){ ah[b]=0.f; ac[b]=0.f; }
    const float4* whr = (const float4*)(Wh + (size_t)r*DM);
    const float4* wcr = (const float4*)(Wc + (size_t)r*DM);
    #pragma nounroll
    for (int kk=0; kk<DM/4; kk++){
      float4 w0 = whr[kk], w1 = wcr[kk];
      #pragma unroll
      for (int b=0;b<BB;b++){
        float4 x = *(const float4*)&sh_x[b][kk*4];
        ah[b] += w0.x*x.x + w0.y*x.y + w0.z*x.z + w0.w*x.w;
        ac[b] += w1.x*x.x + w1.y*x.y + w1.z*x.z + w1.w*x.w;
      }
    }
    float bhv = bh[r], bcv = bc[r];
    if (r < HN){
      #pragma unroll
      for (int b=0;b<BB;b++){
        write_h(sh_h0u, b, r, ah[b] + bhv);
        sh_ct0[b][r] = ac[b] + bcv;
      }
    } else {
      #pragma unroll
      for (int b=0;b<BB;b++){
        write_h(sh_h1u, b, r-HN, ah[b] + bhv);
        sh_ct1[b][r-HN] = ac[b] + bcv;
      }
    }
  }
  __syncthreads();

  // ---- stage context ----
  {
    const float4* src = (const float4*)(ctx + (size_t)gb0*DM);
    ((float4*)&sh_x[0][0])[tid] = src[tid];
  }
  __syncthreads();

  // ---- gates_ctx: thread handles gate rows tid and tid+512 ----
  {
    float a0[BB], a1[BB];
    #pragma unroll
    for (int b=0;b<BB;b++){ a0[b]=0.f; a1[b]=0.f; }
    const float2* wr0 = (const float2*)(Wih0 + (size_t)tid*130 + 2);
    const float2* wr1 = (const float2*)(Wih0 + (size_t)(tid+512)*130 + 2);
    #pragma nounroll
    for (int kk=0; kk<DM/2; kk++){
      float2 w0 = wr0[kk], w1 = wr1[kk];
      #pragma unroll
      for (int b=0;b<BB;b++){
        float2 x = *(const float2*)&sh_x[b][kk*2];
        a0[b] += w0.x*x.x + w0.y*x.y;
        a1[b] += w1.x*x.x + w1.y*x.y;
      }
    }
    float c0 = bih0[tid]     + bhh0[tid];
    float c1 = bih0[tid+512] + bhh0[tid+512];
    #pragma unroll
    for (int b=0;b<BB;b++){
      sh_gctx[b][tid]     = a0[b] + c0;
      sh_gctx[b][tid+512] = a1[b] + c1;
    }
  }

  // ---- per-lane constants (MFMA ownership: wave w, m in 0..1) ----
  float wpr[2][4][2]; float b1r[2][4];
  #pragma unroll
  for (int m=0;m<2;m++){
    int uu = (w*2+m)*16 + col;
    #pragma unroll
    for (int g=0;g<4;g++){
      int j = (g<<8) + uu;
      wpr[m][g][0] = Wih0[(size_t)j*130 + 0];
      wpr[m][g][1] = Wih0[(size_t)j*130 + 1];
      b1r[m][g]    = bih1[j] + bhh1[j];
    }
  }
  const int   p    = (w&3)*16 + col;
  const float bp1p = bp1[p], w20 = Wp2[p], w21 = Wp2[64+p];
  const float bp20 = bp2[0], bp21 = bp2[1];
  __syncthreads();   // gctx + sh_ct complete

  // ---- c-state into MFMA-layout registers ----
  float c0r[2][4], c1r[2][4];   // [m][q]
  #pragma unroll
  for (int m=0;m<2;m++){
    int uu = (w*2+m)*16 + col;
    #pragma unroll
    for (int q=0;q<4;q++){
      c0r[m][q] = sh_ct0[hi*4+q][uu];
      c1r[m][q] = sh_ct1[hi*4+q][uu];
    }
  }

  // ================= 45-step rollout =================
  #pragma nounroll
  for (int t=0; t<NSTEP; t++){
    // ---- P1: A-frags of h0,h1 + pos ----
    s8v a0[8], a1[8];
    #pragma unroll
    for (int kt=0;kt<8;kt++){
      a0[kt] = read_afrag(sh_h0u, col, hi, kt);
      a1[kt] = read_afrag(sh_h1u, col, hi, kt);
    }
    float p0q[4], p1q[4];
    #pragma unroll
    for (int q=0;q<4;q++){
      float2 pp = *(const float2*)&sh_pos[hi*4+q][0];
      p0q[q]=pp.x; p1q[q]=pp.y;
    }
    __syncthreads();

    // ---- P2: layer0 gates + cell ----
    #pragma unroll
    for (int m=0;m<2;m++){
      const int uu = (w*2+m)*16 + col;
      f32x4 ac0, ac1, ac2, ac3;
      #pragma unroll
      for (int q=0;q<4;q++){
        const int b = hi*4+q;
        ac0[q] = sh_gctx[b][uu]     + p0q[q]*wpr[m][0][0] + p1q[q]*wpr[m][0][1];
        ac1[q] = sh_gctx[b][256+uu] + p0q[q]*wpr[m][1][0] + p1q[q]*wpr[m][1][1];
        ac2[q] = sh_gctx[b][512+uu] + p0q[q]*wpr[m][2][0] + p1q[q]*wpr[m][2][1];
        ac3[q] = sh_gctx[b][768+uu] + p0q[q]*wpr[m][3][0] + p1q[q]*wpr[m][3][1];
      }
      const float* wb = Whh0 + (size_t)uu*HN;
      #pragma unroll
      for (int kt=0;kt<8;kt++){
        const int ke = kt*32 + hi*8;
        ac0 = MFMA16(a0[kt], pack8(*(const float4*)(wb+ke),        *(const float4*)(wb+ke+4)),        ac0);
        ac1 = MFMA16(a0[kt], pack8(*(const float4*)(wb+65536+ke),  *(const float4*)(wb+65536+ke+4)),  ac1);
        ac2 = MFMA16(a0[kt], pack8(*(const float4*)(wb+131072+ke), *(const float4*)(wb+131072+ke+4)), ac2);
        ac3 = MFMA16(a0[kt], pack8(*(const float4*)(wb+196608+ke), *(const float4*)(wb+196608+ke+4)), ac3);
      }
      #pragma unroll
      for (int q=0;q<4;q++){
        float iv = sigm(ac0[q]), fv = sigm(ac1[q]);
        float gv = tanhx(ac2[q]), ov = sigm(ac3[q]);
        float cv = fv*c0r[m][q] + iv*gv;
        c0r[m][q] = cv;
        write_h(sh_h0u, hi*4+q, uu, ov*tanhx(cv));
      }
    }
    __syncthreads();

    // ---- P3: layer1 gates + cell ----
    s8v a0n[8];
    #pragma unroll
    for (int kt=0;kt<8;kt++) a0n[kt] = read_afrag(sh_h0u, col, hi, kt);
    #pragma unroll
    for (int m=0;m<2;m++){
      const int uu = (w*2+m)*16 + col;
      f32x4 ac0 = {b1r[m][0],b1r[m][0],b1r[m][0],b1r[m][0]};
      f32x4 ac1 = {b1r[m][1],b1r[m][1],b1r[m][1],b1r[m][1]};
      f32x4 ac2 = {b1r[m][2],b1r[m][2],b1r[m][2],b1r[m][2]};
      f32x4 ac3 = {b1r[m][3],b1r[m][3],b1r[m][3],b1r[m][3]};
      const float* wb1 = Wih1 + (size_t)uu*HN;
      const float* wb2 = Whh1 + (size_t)uu*HN;
      #pragma unroll
      for (int kt=0;kt<8;kt++){
        const int ke = kt*32 + hi*8;
        ac0 = MFMA16(a0n[kt], pack8(*(const float4*)(wb1+ke),        *(const float4*)(wb1+ke+4)),        ac0);
        ac1 = MFMA16(a0n[kt], pack8(*(const float4*)(wb1+65536+ke),  *(const float4*)(wb1+65536+ke+4)),  ac1);
        ac2 = MFMA16(a0n[kt], pack8(*(const float4*)(wb1+131072+ke), *(const float4*)(wb1+131072+ke+4)), ac2);
        ac3 = MFMA16(a0n[kt], pack8(*(const float4*)(wb1+196608+ke), *(const float4*)(wb1+196608+ke+4)), ac3);
      }
      #pragma unroll
      for (int kt=0;kt<8;kt++){
        const int ke = kt*32 + hi*8;
        ac0 = MFMA16(a1[kt], pack8(*(const float4*)(wb2+ke),        *(const float4*)(wb2+ke+4)),        ac0);
        ac1 = MFMA16(a1[kt], pack8(*(const float4*)(wb2+65536+ke),  *(const float4*)(wb2+65536+ke+4)),  ac1);
        ac2 = MFMA16(a1[kt], pack8(*(const float4*)(wb2+131072+ke), *(const float4*)(wb2+131072+ke+4)), ac2);
        ac3 = MFMA16(a1[kt], pack8(*(const float4*)(wb2+196608+ke), *(const float4*)(wb2+196608+ke+4)), ac3);
      }
      #pragma unroll
      for (int q=0;q<4;q++){
        float iv = sigm(ac0[q]), fv = sigm(ac1[q]);
        float gv = tanhx(ac2[q]), ov = sigm(ac3[q]);
        float cv = fv*c1r[m][q] + iv*gv;
        c1r[m][q] = cv;
        write_h(sh_h1u, hi*4+q, uu, ov*tanhx(cv));
      }
    }
    __syncthreads();

    // ---- P4: head (waves 0..3 compute 64 p-units) ----
    if (w < 4){
      s8v a1n[8];
      #pragma unroll
      for (int kt=0;kt<8;kt++) a1n[kt] = read_afrag(sh_h1u, col, hi, kt);
      f32x4 hp = {bp1p, bp1p, bp1p, bp1p};
      const float* wbp = Wp1 + (size_t)p*HN;
      #pragma unroll
      for (int kt=0;kt<8;kt++){
        const int ke = kt*32 + hi*8;
        hp = MFMA16(a1n[kt], pack8(*(const float4*)(wbp+ke), *(const float4*)(wbp+ke+4)), hp);
      }
      #pragma unroll
      for (int q=0;q<4;q++){
        float r  = fmaxf(hp[q], 0.f);
        float s0 = r*w20, s1 = r*w21;
        #pragma unroll
        for (int off=1; off<16; off<<=1){
          s0 += __shfl_xor(s0, off, 64);
          s1 += __shfl_xor(s1, off, 64);
        }
        if (col == 0){ sh_red[w][hi*4+q][0] = s0; sh_red[w][hi*4+q][1] = s1; }
      }
    }
    __syncthreads();

    // ---- P5: combine wave partials, update pos, write out ----
    if (tid < 32){
      int b = tid >> 1, d = tid & 1;
      float s = sh_red[0][b][d] + sh_red[1][b][d] + sh_red[2][b][d] + sh_red[3][b][d]
              + (d ? bp21 : bp20);
      float np = sh_pos[b][d] + s;
      sh_pos[b][d] = np;
      out[((size_t)(gb0+b)*NSTEP + t)*2 + d] = np;
    }
    __syncthreads();
  }
}

extern "C" void kernel_launch(void* const* d_in, const int* in_sizes, int n_in,
                              void* d_out, int out_size, void* d_ws, size_t ws_size,
                              hipStream_t stream) {
  const float* enc  = (const float*)d_in[0];
  const float* pos0 = (const float*)d_in[1];
  const float* ctx  = (const float*)d_in[2];
  const float* Wh   = (const float*)d_in[3];
  const float* bh   = (const float*)d_in[4];
  const float* Wc   = (const float*)d_in[5];
  const float* bc   = (const float*)d_in[6];
  const float* Wih0 = (const float*)d_in[7];
  const float* Whh0 = (const float*)d_in[8];
  const float* bih0 = (const float*)d_in[9];
  const float* bhh0 = (const float*)d_in[10];
  const float* Wih1 = (const float*)d_in[11];
  const float* Whh1 = (const float*)d_in[12];
  const float* bih1 = (const float*)d_in[13];
  const float* bhh1 = (const float*)d_in[14];
  const float* Wp1  = (const float*)d_in[15];
  const float* bp1  = (const float*)d_in[16];
  const float* Wp2  = (const float*)d_in[17];
  const float* bp2  = (const float*)d_in[18];
  float* out = (float*)d_out;

  const int B = 4096;
  hipLaunchKernelGGL(traj_mfma, dim3(B / BB), dim3(TPB), 0, stream,
                     enc, pos0, ctx, Wh, bh, Wc, bc, Wih0, Whh0, bih0, bhh0,
                     Wih1, Whh1, bih1, bhh1, Wp1, Wp2, bp1, bp2, out);
}